// Round 3
// baseline (394.653 us; speedup 1.0000x reference)
//
#include <hip/hip_runtime.h>
#include <math.h>

#define Bn 512
#define Ln 20
#define Nn 100
#define Dn 64
#define En 32
#define Hn 3

// ---------------- K0a: transposes + first-level folded products ----------------
__global__ __launch_bounds__(256) void k0a_prep(
    const float* __restrict__ M_r, const float* __restrict__ Wu_r, const float* __restrict__ bu_r,
    const float* __restrict__ Wi_r,
    const float* __restrict__ M_w, const float* __restrict__ Wu_w, const float* __restrict__ bu_w,
    const float* __restrict__ Wi_w, const float* __restrict__ bi_w,
    const float* __restrict__ Wu_f, const float* __restrict__ Wi_f,
    const float* __restrict__ ufc, const float* __restrict__ ifc,
    const float* __restrict__ ufc2, const float* __restrict__ ifc2,
    float* __restrict__ WiT_r, float* __restrict__ WMr, float* __restrict__ bMr,
    float* __restrict__ P, float* __restrict__ Q, float* __restrict__ MB, float* __restrict__ MTB,
    float* __restrict__ WuT_f, float* __restrict__ WiT_f,
    float* __restrict__ ufcT, float* __restrict__ ifcT,
    float* __restrict__ u_fcT, float* __restrict__ i_fcT)
{
    int t = blockIdx.x * blockDim.x + threadIdx.x;
    int stride = gridDim.x * blockDim.x;
    // WMr[h][c][e] = sum_d Wu_r[h][d][c] * M_r[h][d][e]
    for (int k = t; k < Hn*Dn*Dn; k += stride) {
        int h = k >> 12, r = k & 4095; int c = r >> 6, e = r & 63;
        const float* Wu = Wu_r + h*4096; const float* M = M_r + h*4096;
        float a = 0.f;
        for (int d = 0; d < Dn; ++d) a += Wu[d*Dn + c] * M[d*Dn + e];
        WMr[k] = a;
    }
    // P[h][d][b] = sum_e M_w[h][d][e] * Wi_w[h][e][b]
    for (int k = t; k < Hn*Dn*Dn; k += stride) {
        int h = k >> 12, r = k & 4095; int d = r >> 6, bb = r & 63;
        const float* M = M_w + h*4096; const float* Wi = Wi_w + h*4096;
        float a = 0.f;
        for (int e = 0; e < Dn; ++e) a += M[d*Dn + e] * Wi[e*Dn + bb];
        P[k] = a;
    }
    // Q[h][d][b] = sum_e M_w[h][e][d] * Wu_w[h][e][b]
    for (int k = t; k < Hn*Dn*Dn; k += stride) {
        int h = k >> 12, r = k & 4095; int d = r >> 6, bb = r & 63;
        const float* M = M_w + h*4096; const float* Wu = Wu_w + h*4096;
        float a = 0.f;
        for (int e = 0; e < Dn; ++e) a += M[e*Dn + d] * Wu[e*Dn + bb];
        Q[k] = a;
    }
    // WiT_r[h][c][dp] = Wi_r[h][dp][c]
    for (int k = t; k < Hn*Dn*Dn; k += stride) {
        int h = k >> 12, r = k & 4095; int c = r >> 6, dp = r & 63;
        WiT_r[k] = Wi_r[h*4096 + dp*Dn + c];
    }
    // bMr[h][e] = sum_d bu_r[h][d]*M_r[h][d][e];  MB[h][d]=sum_e M_w[h][d][e]*bi_w[h][e]; MTB[h][d]=sum_e M_w[h][e][d]*bu_w[h][e]
    for (int k = t; k < Hn*Dn; k += stride) {
        int h = k >> 6, e = k & 63;
        const float* M = M_r + h*4096;
        float a = 0.f;
        for (int d = 0; d < Dn; ++d) a += bu_r[h*Dn + d] * M[d*Dn + e];
        bMr[k] = a;
        const float* Mw_ = M_w + h*4096;
        float p = 0.f, q = 0.f;
        for (int d2 = 0; d2 < Dn; ++d2) {
            p += Mw_[e*Dn + d2] * bi_w[h*Dn + d2];   // here "e" plays role of d: MB[h][d]
            q += Mw_[d2*Dn + e] * bu_w[h*Dn + d2];
        }
        MB[k] = p; MTB[k] = q;
    }
    // f-side transposes
    for (int k = t; k < Hn*En*En; k += stride) {
        int h = k / (En*En); int rem = k - h*En*En;
        int a = rem >> 5, c = rem & 31;
        int src = h*En*En + c*En + a;
        WuT_f[k] = Wu_f[src]; WiT_f[k] = Wi_f[src];
    }
    for (int k = t; k < Dn*En; k += stride) {
        int d = k >> 5, e = k & 31;
        ufcT[k] = ufc[e*Dn + d]; ifcT[k] = ifc[e*Dn + d];
    }
    for (int k = t; k < 96*En; k += stride) {
        int kk = k >> 5, e = k & 31;
        u_fcT[k] = ufc2[e*96 + kk]; i_fcT[k] = ifc2[e*96 + kk];
    }
}

// ---------------- K0b: second-level folded products ----------------
__global__ __launch_bounds__(256) void k0b_prep(
    const float* __restrict__ Wu_w, const float* __restrict__ Wi_w,
    const float* __restrict__ P, const float* __restrict__ Q,
    const float* __restrict__ MB, const float* __restrict__ MTB,
    float* __restrict__ GuT, float* __restrict__ GiT,
    float* __restrict__ gu_v, float* __restrict__ gi_v)
{
    int t = blockIdx.x * blockDim.x + threadIdx.x;
    int stride = gridDim.x * blockDim.x;
    // GuT[h][b][a] = sum_d Wu_w[h][d][a] * P[h][d][b]
    for (int k = t; k < Hn*Dn*Dn; k += stride) {
        int h = k >> 12, r = k & 4095; int bb = r >> 6, a = r & 63;
        const float* Wu = Wu_w + h*4096; const float* Pp = P + h*4096;
        float s = 0.f;
        for (int d = 0; d < Dn; ++d) s += Wu[d*Dn + a] * Pp[d*Dn + bb];
        GuT[k] = s;
    }
    // GiT[h][b][a] = sum_d Wi_w[h][d][a] * Q[h][d][b]
    for (int k = t; k < Hn*Dn*Dn; k += stride) {
        int h = k >> 12, r = k & 4095; int bb = r >> 6, a = r & 63;
        const float* Wi = Wi_w + h*4096; const float* Qp = Q + h*4096;
        float s = 0.f;
        for (int d = 0; d < Dn; ++d) s += Wi[d*Dn + a] * Qp[d*Dn + bb];
        GiT[k] = s;
    }
    for (int k = t; k < Hn*Dn; k += stride) {
        int h = k >> 6, a = k & 63;
        const float* Wu = Wu_w + h*4096; const float* Wi = Wi_w + h*4096;
        float s1 = 0.f, s2 = 0.f;
        for (int d = 0; d < Dn; ++d) {
            s1 += Wu[d*Dn + a] * MB[h*Dn + d];
            s2 += Wi[d*Dn + a] * MTB[h*Dn + d];
        }
        gu_v[k] = s1; gi_v[k] = s2;
    }
}

// ---------------- K1: review gate, persistent grid-stride ----------------
__global__ __launch_bounds__(512) void k1_gate(
    const int* __restrict__ urev, const int* __restrict__ irev,
    const float* __restrict__ utab, const float* __restrict__ itab,
    const float* __restrict__ W1, const float* __restrict__ b1v,
    const float* __restrict__ W2, const float* __restrict__ b2v,
    float* __restrict__ ugo, float* __restrict__ igo)
{
    __shared__ float w1s[Dn][Dn+1];
    __shared__ float w2s[Dn][Dn+1];
    int tid = threadIdx.x;
    for (int k = tid; k < Dn*Dn; k += 512) {
        int r = k >> 6, c = k & 63;
        w1s[r][c] = W1[k]; w2s[r][c] = W2[k];
    }
    __syncthreads();
    int ln = tid & 63;
    int wv = tid >> 6;
    float b1 = b1v[ln], b2 = b2v[ln];
    int nW = (gridDim.x * 512) >> 6;
    for (int gw = (blockIdx.x << 3) + wv; gw < 2*Bn*Ln; gw += nW) {
        int side = (gw >= Bn*Ln) ? 1 : 0;
        int r = gw - side*(Bn*Ln);
        const int* rev = side ? irev : urev;
        const float* tab = side ? itab : utab;
        int i0 = rev[r*Nn + ln];
        int i1 = (ln < Nn - 64) ? rev[r*Nn + 64 + ln] : 0;
        float acc = 0.f;
        #pragma unroll
        for (int n = 0; n < 64; ++n) {
            int idx = __shfl(i0, n);
            acc += tab[idx*Dn + ln];
        }
        #pragma unroll
        for (int n = 0; n < Nn - 64; ++n) {
            int idx = __shfl(i1, n);
            acc += tab[idx*Dn + ln];
        }
        float t1 = b1, t2 = b2;
        #pragma unroll 8
        for (int d = 0; d < Dn; ++d) {
            float sv = __shfl(acc, d);
            t1 += sv * w1s[ln][d];
            t2 += sv * w2s[ln][d];
        }
        float g = (1.f / (1.f + expf(-t1))) * tanhf(t2);
        (side ? igo : ugo)[r*Dn + ln] = g;
    }
}

// ---------------- K2: per-(b,h) pipeline, folded ----------------
__global__ __launch_bounds__(256) void k2_coatt(
    const int* __restrict__ urev, const int* __restrict__ irev,
    const int* __restrict__ uids, const int* __restrict__ iids,
    const int* __restrict__ ttype, const int* __restrict__ tmonth,
    const float* __restrict__ gu_all, const float* __restrict__ gi_all,
    const float* __restrict__ utab, const float* __restrict__ itab,
    const float* __restrict__ uid_tab, const float* __restrict__ iid_tab,
    const float* __restrict__ type_tab, const float* __restrict__ month_tab,
    const float* __restrict__ ug_in, const float* __restrict__ ig_in,
    const float* __restrict__ WMr, const float* __restrict__ bMr,
    const float* __restrict__ WiT_r, const float* __restrict__ bi_r,
    const float* __restrict__ GuT, const float* __restrict__ GiT,
    const float* __restrict__ gu_v, const float* __restrict__ gi_v,
    const float* __restrict__ M_f, const float* __restrict__ bu_f, const float* __restrict__ bi_f,
    const float* __restrict__ WuT_f, const float* __restrict__ WiT_f,
    const float* __restrict__ ufcT, const float* __restrict__ ufc_bv,
    const float* __restrict__ ifcT, const float* __restrict__ ifc_bv,
    float* __restrict__ feas, float* __restrict__ outp)
{
    __shared__ __align__(16) float big[13000];
    __shared__ float S[Ln][Ln];
    __shared__ int   lstar[2];
    __shared__ float vecs[4][Dn];     // uwbar, iwbar, wu, wi
    __shared__ float sc[2][Nn];
    __shared__ float uif[2][Dn];
    __shared__ float re[2][En], fe[4][En];
    __shared__ float u3[2][En], i3[4][En], A3[2][En];
    __shared__ float att[6];

    float* ug_sp = big;               // 1280
    float* ig_sp = big + 1280;        // 1280
    float* pu_sp = big + 2560;        // 2x20x64 = 2560
    float* pi_sp = big + 5120;        // 2560
    float* Ab_sp = big + 7680;        // 20x65 = 1300
    float* iv_sp = big + 8980;        // 1300
    float* uw    = big;               // 100x65 = 6500 (phase 2 overlay)
    float* iw    = big + 6500;        // 6500

    int tid = threadIdx.x;
    int bh = blockIdx.x;
    int b = bh / Hn;
    int h = bh - b*Hn;
    int ln = tid & 63;
    int wv = tid >> 6;

    if (tid < 4*En) {
        int rrow = tid >> 5, e = tid & 31;
        float v;
        if (rrow == 0) v = uid_tab[uids[b]*En + e];
        else if (rrow == 1) v = iid_tab[iids[b]*En + e];
        else if (rrow == 2) v = type_tab[ttype[b]*En + e];
        else v = month_tab[tmonth[b]*En + e];
        fe[rrow][e] = v;
    }
    {   // load gates (contiguous) as float4
        const float4* su = (const float4*)(ug_in + b*Ln*Dn);
        const float4* si = (const float4*)(ig_in + b*Ln*Dn);
        float4* du = (float4*)ug_sp;
        float4* di = (float4*)ig_sp;
        for (int k = tid; k < (Ln*Dn)/4; k += 256) { du[k] = su[k]; di[k] = si[k]; }
    }
    __syncthreads();

    // ---- phase 1: Ab = ug@WMr + bMr ; iv = ig@WiT + bi  (register-tiled over l) ----
    {
        int mat = wv & 1;               // 0: u->Ab via WMr, 1: i->iv via WiT
        int dh  = wv >> 1;              // d half
        const float* W = (mat ? (WiT_r + h*4096) : (WMr + h*4096)) + dh*32*Dn + ln;
        const float* X = (mat ? ig_sp : ug_sp) + dh*32;
        float acc[Ln];
        #pragma unroll
        for (int l = 0; l < Ln; ++l) acc[l] = 0.f;
        for (int dd = 0; dd < 32; dd += 4) {
            float w0 = W[(dd+0)*Dn];
            float w1 = W[(dd+1)*Dn];
            float w2 = W[(dd+2)*Dn];
            float w3 = W[(dd+3)*Dn];
            #pragma unroll
            for (int l = 0; l < Ln; ++l) {
                float4 x = *(const float4*)(X + l*Dn + dd);
                acc[l] += x.x*w0 + x.y*w1 + x.z*w2 + x.w*w3;
            }
        }
        float* po = (mat ? pi_sp : pu_sp) + dh*(Ln*Dn) + ln;
        #pragma unroll
        for (int l = 0; l < Ln; ++l) po[l*Dn] = acc[l];
    }
    __syncthreads();
    for (int k = tid; k < 2*Ln*Dn; k += 256) {
        int mm = (k >= Ln*Dn);
        int r = k - (mm ? Ln*Dn : 0);
        int l = r >> 6, ee = r & 63;
        if (!mm) Ab_sp[l*65 + ee] = pu_sp[l*Dn + ee] + pu_sp[Ln*Dn + l*Dn + ee] + bMr[h*Dn + ee];
        else     iv_sp[l*65 + ee] = pi_sp[l*Dn + ee] + pi_sp[Ln*Dn + l*Dn + ee] + bi_r[h*Dn + ee];
    }
    __syncthreads();
    for (int k = tid; k < Ln*Ln; k += 256) {
        int l = k / Ln, m = k - l*Ln;
        float a = 0.f;
        for (int e = 0; e < Dn; ++e) a += Ab_sp[l*65 + e] * iv_sp[m*65 + e];
        S[l][m] = a;
    }
    __syncthreads();
    // ---- argmax(rowmax + gumbel) via wave reduce ----
    if (wv == 0) {
        float v = -3.4e38f;
        if (ln < Ln) {
            float mx = S[ln][0];
            #pragma unroll
            for (int m = 1; m < Ln; ++m) mx = fmaxf(mx, S[ln][m]);
            v = mx + gu_all[(h*Bn + b)*Ln + ln];
        }
        int idx = ln;
        #pragma unroll
        for (int off = 32; off > 0; off >>= 1) {
            float ov = __shfl_down(v, off);
            int oi = __shfl_down(idx, off);
            if (ov > v || (ov == v && oi < idx)) { v = ov; idx = oi; }
        }
        if (ln == 0) lstar[0] = idx;
    } else if (wv == 1) {
        float v = -3.4e38f;
        if (ln < Ln) {
            float mx = S[0][ln];
            #pragma unroll
            for (int l = 1; l < Ln; ++l) mx = fmaxf(mx, S[l][ln]);
            v = mx + gi_all[(h*Bn + b)*Ln + ln];
        }
        int idx = ln;
        #pragma unroll
        for (int off = 32; off > 0; off >>= 1) {
            float ov = __shfl_down(v, off);
            int oi = __shfl_down(idx, off);
            if (ov > v || (ov == v && oi < idx)) { v = ov; idx = oi; }
        }
        if (ln == 0) lstar[1] = idx;
    }
    __syncthreads();
    // ---- phase 2: gather selected reviews' words ----
    {
        const int* up = urev + (b*Ln + lstar[0])*Nn;
        const int* ip = irev + (b*Ln + lstar[1])*Nn;
        for (int k = tid; k < Nn*Dn; k += 256) {
            int n = k >> 6, d = k & 63;
            uw[n*65 + d] = utab[up[n]*Dn + d];
            iw[n*65 + d] = itab[ip[n]*Dn + d];
        }
    }
    __syncthreads();
    if (tid < Dn) {
        float a = 0.f;
        for (int n = 0; n < Nn; ++n) a += uw[n*65 + tid];
        vecs[0][tid] = a * (1.f/Nn);
    } else if (tid < 2*Dn) {
        int d = tid - Dn;
        float a = 0.f;
        for (int n = 0; n < Nn; ++n) a += iw[n*65 + d];
        vecs[1][d] = a * (1.f/Nn);
    }
    __syncthreads();
    // wu = GuT^T@iwbar + gu ; wi = GiT^T@uwbar + gi   (folded full chain)
    if (tid < Dn) {
        float a = gu_v[h*Dn + tid];
        for (int bb = 0; bb < Dn; ++bb) a += GuT[h*4096 + bb*Dn + tid] * vecs[1][bb];
        vecs[2][tid] = a;
    } else if (tid < 2*Dn) {
        int aa = tid - Dn;
        float a = gi_v[h*Dn + aa];
        for (int bb = 0; bb < Dn; ++bb) a += GiT[h*4096 + bb*Dn + aa] * vecs[0][bb];
        vecs[3][aa] = a;
    }
    __syncthreads();
    if (tid < Nn) {                        // u_score2[n] = uw[n]·wu (+const dropped)
        float a = 0.f;
        for (int d = 0; d < Dn; ++d) a += uw[tid*65 + d] * vecs[2][d];
        sc[0][tid] = a;
    } else if (tid >= 128 && tid < 128 + Nn) {
        int n = tid - 128;
        float a = 0.f;
        for (int d = 0; d < Dn; ++d) a += iw[n*65 + d] * vecs[3][d];
        sc[1][n] = a;
    }
    __syncthreads();
    // wave-parallel softmax over N=100 (waves 0 and 2)
    if (wv == 0 || wv == 2) {
        float* s = sc[wv >> 1];
        float x0 = s[ln];
        float x1 = (ln < Nn - 64) ? s[64 + ln] : -3.4e38f;
        float mx = fmaxf(x0, x1);
        #pragma unroll
        for (int off = 32; off > 0; off >>= 1) mx = fmaxf(mx, __shfl_xor(mx, off));
        float e0 = expf(x0 - mx);
        float e1 = (ln < Nn - 64) ? expf(x1 - mx) : 0.f;
        float sum = e0 + e1;
        #pragma unroll
        for (int off = 32; off > 0; off >>= 1) sum += __shfl_xor(sum, off);
        float inv = 1.f / sum;
        s[ln] = e0 * inv;
        if (ln < Nn - 64) s[64 + ln] = e1 * inv;
    }
    __syncthreads();
    if (tid < Dn) {
        float a = 0.f;
        for (int n = 0; n < Nn; ++n) a += sc[0][n] * uw[n*65 + tid];
        uif[0][tid] = a;
    } else if (tid < 2*Dn) {
        int d = tid - Dn;
        float a = 0.f;
        for (int n = 0; n < Nn; ++n) a += sc[1][n] * uw[n*65 + d];   // reference quirk: uw both times
        uif[1][d] = a;
    }
    __syncthreads();
    if (tid < En) {
        float a = ufc_bv[tid];
        for (int d = 0; d < Dn; ++d) a += uif[0][d] * ufcT[d*En + tid];
        re[0][tid] = fmaxf(a, 0.f);
    } else if (tid < 2*En) {
        int e = tid - En;
        float a = ifc_bv[e];
        for (int d = 0; d < Dn; ++d) a += uif[1][d] * ifcT[d*En + e];
        re[1][e] = fmaxf(a, 0.f);
    }
    __syncthreads();
    // ---- phase 3: coatt_f (2x4, avg pooling) ----
    const float* WuTf = WuT_f + h*En*En;
    const float* WiTf = WiT_f + h*En*En;
    const float* Mf   = M_f  + h*En*En;
    const float* buf_ = bu_f + h*En;
    const float* bif_ = bi_f + h*En;
    if (tid < 2*En) {
        int l = tid >> 5, e = tid & 31;
        float a = buf_[e];
        for (int j = 0; j < En; ++j) a += re[l][j] * WuTf[j*En + e];
        u3[l][e] = a;
    } else if (tid < 6*En) {
        int t2 = tid - 2*En;
        int m = t2 >> 5, e = t2 & 31;
        float a = bif_[e];
        for (int j = 0; j < En; ++j) a += fe[m][j] * WiTf[j*En + e];
        i3[m][e] = a;
    }
    __syncthreads();
    if (tid < 2*En) {
        int l = tid >> 5, e = tid & 31;
        float a = 0.f;
        for (int d = 0; d < En; ++d) a += u3[l][d] * Mf[d*En + e];
        A3[l][e] = a;
    }
    __syncthreads();
    if (tid == 0) {
        float S3[2][4];
        for (int l = 0; l < 2; ++l)
            for (int m = 0; m < 4; ++m) {
                float a = 0.f;
                for (int e = 0; e < En; ++e) a += A3[l][e] * i3[m][e];
                S3[l][m] = a;
            }
        float us0 = (S3[0][0] + S3[0][1] + S3[0][2] + S3[0][3]) * 0.25f;
        float us1 = (S3[1][0] + S3[1][1] + S3[1][2] + S3[1][3]) * 0.25f;
        float mx = fmaxf(us0, us1);
        float e0 = expf(us0 - mx), e1 = expf(us1 - mx);
        float inv = 1.f / (e0 + e1);
        att[0] = e0 * inv; att[1] = e1 * inv;
        float is_[4]; float mxi = -3.4e38f;
        for (int m = 0; m < 4; ++m) { is_[m] = (S3[0][m] + S3[1][m]) * 0.5f; mxi = fmaxf(mxi, is_[m]); }
        float ssum = 0.f, ee[4];
        for (int m = 0; m < 4; ++m) { ee[m] = expf(is_[m] - mxi); ssum += ee[m]; }
        float invi = 1.f / ssum;
        for (int m = 0; m < 4; ++m) att[2 + m] = ee[m] * invi;
    }
    __syncthreads();
    if (tid < En) {
        feas[b*96 + h*En + tid] = re[0][tid] * att[0];
    }
    if (h == 2) {
        if (tid >= 32 && tid < 64)        { int e = tid - 32;  outp[b*96 + e]              = fe[0][e] * att[2]; }
        else if (tid >= 64 && tid < 96)   { int e = tid - 64;  outp[b*96 + 32 + e]         = fe[2][e] * att[4]; }
        else if (tid >= 96 && tid < 128)  { int e = tid - 96;  outp[Bn*96 + b*96 + e]      = fe[1][e] * att[3]; }
        else if (tid >= 128 && tid < 160) { int e = tid - 128; outp[Bn*96 + b*96 + 32 + e] = fe[3][e] * att[5]; }
    }
}

// ---------------- K3: final linears ----------------
__global__ __launch_bounds__(64) void k3_final(
    const float* __restrict__ feas,
    const float* __restrict__ u_fcT, const float* __restrict__ u_fc_bv,
    const float* __restrict__ i_fcT, const float* __restrict__ i_fc_bv,
    float* __restrict__ outp)
{
    __shared__ float f[96];
    int b = blockIdx.x, tid = threadIdx.x;
    for (int k = tid; k < 96; k += 64) f[k] = feas[b*96 + k];
    __syncthreads();
    if (tid < 32) {
        float a = u_fc_bv[tid];
        for (int k = 0; k < 96; ++k) a += f[k] * u_fcT[k*32 + tid];
        outp[b*96 + 64 + tid] = a;
    } else {
        int e = tid - 32;
        float a = i_fc_bv[e];
        for (int k = 0; k < 96; ++k) a += f[k] * i_fcT[k*32 + e];
        outp[Bn*96 + b*96 + 64 + e] = a;
    }
}

extern "C" void kernel_launch(void* const* d_in, const int* in_sizes, int n_in,
                              void* d_out, int out_size, void* d_ws, size_t ws_size,
                              hipStream_t stream)
{
    const int* urev = (const int*)d_in[0];
    const int* irev = (const int*)d_in[1];
    const int* uids = (const int*)d_in[2];
    const int* iids = (const int*)d_in[3];
    const int* ttype = (const int*)d_in[4];
    const int* tmonth = (const int*)d_in[5];
    const float* gu = (const float*)d_in[6];
    const float* gi = (const float*)d_in[7];
    const float* utab = (const float*)d_in[8];
    const float* itab = (const float*)d_in[9];
    const float* uid_tab = (const float*)d_in[10];
    const float* iid_tab = (const float*)d_in[11];
    const float* type_tab = (const float*)d_in[12];
    const float* month_tab = (const float*)d_in[13];
    const float* fc_g1_w = (const float*)d_in[14];
    const float* fc_g1_b = (const float*)d_in[15];
    const float* fc_g2_w = (const float*)d_in[16];
    const float* fc_g2_b = (const float*)d_in[17];
    const float* M_r = (const float*)d_in[18];
    const float* Wu_r = (const float*)d_in[19];
    const float* bu_r = (const float*)d_in[20];
    const float* Wi_r = (const float*)d_in[21];
    const float* bi_r = (const float*)d_in[22];
    const float* M_w = (const float*)d_in[23];
    const float* Wu_w = (const float*)d_in[24];
    const float* bu_w = (const float*)d_in[25];
    const float* Wi_w = (const float*)d_in[26];
    const float* bi_w = (const float*)d_in[27];
    const float* M_f = (const float*)d_in[28];
    const float* Wu_f = (const float*)d_in[29];
    const float* bu_f = (const float*)d_in[30];
    const float* Wi_f = (const float*)d_in[31];
    const float* bi_f = (const float*)d_in[32];
    const float* ufc_w = (const float*)d_in[33];
    const float* ufc_b = (const float*)d_in[34];
    const float* ifc_w = (const float*)d_in[35];
    const float* ifc_b = (const float*)d_in[36];
    const float* u_fc_w = (const float*)d_in[37];
    const float* u_fc_b = (const float*)d_in[38];
    const float* i_fc_w = (const float*)d_in[39];
    const float* i_fc_b = (const float*)d_in[40];
    (void)in_sizes; (void)n_in; (void)out_size; (void)ws_size;

    float* ws = (float*)d_ws;
    float* ugo   = ws;                         // B*L*D
    float* igo   = ugo + Bn*Ln*Dn;
    float* feas  = igo + Bn*Ln*Dn;             // B*96
    float* WiT_r = feas + Bn*96;
    float* WMr   = WiT_r + Hn*Dn*Dn;
    float* bMr   = WMr + Hn*Dn*Dn;
    float* P     = bMr + Hn*Dn;
    float* Q     = P + Hn*Dn*Dn;
    float* MB    = Q + Hn*Dn*Dn;
    float* MTB   = MB + Hn*Dn;
    float* GuT   = MTB + Hn*Dn;
    float* GiT   = GuT + Hn*Dn*Dn;
    float* gu_v  = GiT + Hn*Dn*Dn;
    float* gi_v  = gu_v + Hn*Dn;
    float* WuT_f = gi_v + Hn*Dn;
    float* WiT_f = WuT_f + Hn*En*En;
    float* ufcT  = WiT_f + Hn*En*En;
    float* ifcT  = ufcT + Dn*En;
    float* u_fcT = ifcT + Dn*En;
    float* i_fcT = u_fcT + 96*En;

    hipLaunchKernelGGL(k0a_prep, dim3(48), dim3(256), 0, stream,
        M_r, Wu_r, bu_r, Wi_r, M_w, Wu_w, bu_w, Wi_w, bi_w,
        Wu_f, Wi_f, ufc_w, ifc_w, u_fc_w, i_fc_w,
        WiT_r, WMr, bMr, P, Q, MB, MTB, WuT_f, WiT_f, ufcT, ifcT, u_fcT, i_fcT);

    hipLaunchKernelGGL(k0b_prep, dim3(48), dim3(256), 0, stream,
        Wu_w, Wi_w, P, Q, MB, MTB, GuT, GiT, gu_v, gi_v);

    hipLaunchKernelGGL(k1_gate, dim3(1024), dim3(512), 0, stream,
        urev, irev, utab, itab, fc_g1_w, fc_g1_b, fc_g2_w, fc_g2_b, ugo, igo);

    hipLaunchKernelGGL(k2_coatt, dim3(Bn*Hn), dim3(256), 0, stream,
        urev, irev, uids, iids, ttype, tmonth, gu, gi, utab, itab,
        uid_tab, iid_tab, type_tab, month_tab, ugo, igo,
        WMr, bMr, WiT_r, bi_r, GuT, GiT, gu_v, gi_v,
        M_f, bu_f, bi_f, WuT_f, WiT_f,
        ufcT, ufc_b, ifcT, ifc_b, feas, (float*)d_out);

    hipLaunchKernelGGL(k3_final, dim3(Bn), dim3(64), 0, stream,
        feas, u_fcT, u_fc_b, i_fcT, i_fc_b, (float*)d_out);
}

// Round 6
// 326.544 us; speedup vs baseline: 1.2086x; 1.2086x over previous
//
#include <hip/hip_runtime.h>
#include <math.h>

#define Bn 512
#define Ln 20
#define Nn 100
#define Dn 64
#define En 32
#define Hn 3

// ---------------- K0a: transposes + first-level folded products ----------------
__global__ __launch_bounds__(256) void k0a_prep(
    const float* __restrict__ M_r, const float* __restrict__ Wu_r, const float* __restrict__ bu_r,
    const float* __restrict__ Wi_r,
    const float* __restrict__ M_w, const float* __restrict__ Wu_w, const float* __restrict__ bu_w,
    const float* __restrict__ Wi_w, const float* __restrict__ bi_w,
    const float* __restrict__ Wu_f, const float* __restrict__ Wi_f,
    const float* __restrict__ ufc, const float* __restrict__ ifc,
    const float* __restrict__ ufc2, const float* __restrict__ ifc2,
    float* __restrict__ WiT_r, float* __restrict__ WMr, float* __restrict__ bMr,
    float* __restrict__ P, float* __restrict__ Q, float* __restrict__ MB, float* __restrict__ MTB,
    float* __restrict__ WuT_f, float* __restrict__ WiT_f,
    float* __restrict__ ufcT, float* __restrict__ ifcT,
    float* __restrict__ u_fcT, float* __restrict__ i_fcT)
{
    int t = blockIdx.x * blockDim.x + threadIdx.x;
    int stride = gridDim.x * blockDim.x;
    // WMr[h][c][e] = sum_d Wu_r[h][d][c] * M_r[h][d][e]
    for (int k = t; k < Hn*Dn*Dn; k += stride) {
        int h = k >> 12, r = k & 4095; int c = r >> 6, e = r & 63;
        const float* Wu = Wu_r + h*4096; const float* M = M_r + h*4096;
        float a = 0.f;
        for (int d = 0; d < Dn; ++d) a += Wu[d*Dn + c] * M[d*Dn + e];
        WMr[k] = a;
    }
    // P[h][d][b] = sum_e M_w[h][d][e] * Wi_w[h][e][b]
    for (int k = t; k < Hn*Dn*Dn; k += stride) {
        int h = k >> 12, r = k & 4095; int d = r >> 6, bb = r & 63;
        const float* M = M_w + h*4096; const float* Wi = Wi_w + h*4096;
        float a = 0.f;
        for (int e = 0; e < Dn; ++e) a += M[d*Dn + e] * Wi[e*Dn + bb];
        P[k] = a;
    }
    // Q[h][d][b] = sum_e M_w[h][e][d] * Wu_w[h][e][b]
    for (int k = t; k < Hn*Dn*Dn; k += stride) {
        int h = k >> 12, r = k & 4095; int d = r >> 6, bb = r & 63;
        const float* M = M_w + h*4096; const float* Wu = Wu_w + h*4096;
        float a = 0.f;
        for (int e = 0; e < Dn; ++e) a += M[e*Dn + d] * Wu[e*Dn + bb];
        Q[k] = a;
    }
    // WiT_r[h][c][dp] = Wi_r[h][dp][c]
    for (int k = t; k < Hn*Dn*Dn; k += stride) {
        int h = k >> 12, r = k & 4095; int c = r >> 6, dp = r & 63;
        WiT_r[k] = Wi_r[h*4096 + dp*Dn + c];
    }
    // bMr[h][e] = sum_d bu_r[h][d]*M_r[h][d][e];  MB[h][d]=sum_e M_w[h][d][e]*bi_w[h][e]; MTB[h][d]=sum_e M_w[h][e][d]*bu_w[h][e]
    for (int k = t; k < Hn*Dn; k += stride) {
        int h = k >> 6, e = k & 63;
        const float* M = M_r + h*4096;
        float a = 0.f;
        for (int d = 0; d < Dn; ++d) a += bu_r[h*Dn + d] * M[d*Dn + e];
        bMr[k] = a;
        const float* Mw_ = M_w + h*4096;
        float p = 0.f, q = 0.f;
        for (int d2 = 0; d2 < Dn; ++d2) {
            p += Mw_[e*Dn + d2] * bi_w[h*Dn + d2];
            q += Mw_[d2*Dn + e] * bu_w[h*Dn + d2];
        }
        MB[k] = p; MTB[k] = q;
    }
    // f-side transposes
    for (int k = t; k < Hn*En*En; k += stride) {
        int h = k / (En*En); int rem = k - h*En*En;
        int a = rem >> 5, c = rem & 31;
        int src = h*En*En + c*En + a;
        WuT_f[k] = Wu_f[src]; WiT_f[k] = Wi_f[src];
    }
    for (int k = t; k < Dn*En; k += stride) {
        int d = k >> 5, e = k & 31;
        ufcT[k] = ufc[e*Dn + d]; ifcT[k] = ifc[e*Dn + d];
    }
    for (int k = t; k < 96*En; k += stride) {
        int kk = k >> 5, e = k & 31;
        u_fcT[k] = ufc2[e*96 + kk]; i_fcT[k] = ifc2[e*96 + kk];
    }
}

// ---------------- K0b: second-level folded products ----------------
__global__ __launch_bounds__(256) void k0b_prep(
    const float* __restrict__ Wu_w, const float* __restrict__ Wi_w,
    const float* __restrict__ P, const float* __restrict__ Q,
    const float* __restrict__ MB, const float* __restrict__ MTB,
    float* __restrict__ GuT, float* __restrict__ GiT,
    float* __restrict__ gu_v, float* __restrict__ gi_v)
{
    int t = blockIdx.x * blockDim.x + threadIdx.x;
    int stride = gridDim.x * blockDim.x;
    for (int k = t; k < Hn*Dn*Dn; k += stride) {
        int h = k >> 12, r = k & 4095; int bb = r >> 6, a = r & 63;
        const float* Wu = Wu_w + h*4096; const float* Pp = P + h*4096;
        float s = 0.f;
        for (int d = 0; d < Dn; ++d) s += Wu[d*Dn + a] * Pp[d*Dn + bb];
        GuT[k] = s;
    }
    for (int k = t; k < Hn*Dn*Dn; k += stride) {
        int h = k >> 12, r = k & 4095; int bb = r >> 6, a = r & 63;
        const float* Wi = Wi_w + h*4096; const float* Qp = Q + h*4096;
        float s = 0.f;
        for (int d = 0; d < Dn; ++d) s += Wi[d*Dn + a] * Qp[d*Dn + bb];
        GiT[k] = s;
    }
    for (int k = t; k < Hn*Dn; k += stride) {
        int h = k >> 6, a = k & 63;
        const float* Wu = Wu_w + h*4096; const float* Wi = Wi_w + h*4096;
        float s1 = 0.f, s2 = 0.f;
        for (int d = 0; d < Dn; ++d) {
            s1 += Wu[d*Dn + a] * MB[h*Dn + d];
            s2 += Wi[d*Dn + a] * MTB[h*Dn + d];
        }
        gu_v[k] = s1; gi_v[k] = s2;
    }
}

// ---------------- K1a: gather-sum only — max memory-level parallelism ----------------
// 1 wave per (side,b,l) row. Each lane owns a float4 quad of D; 25 independent
// dwordx4 loads issued as a batch (load-all-then-sum), quad-reduce via shfl_xor.
__global__ __launch_bounds__(256) void k1a_gsum(
    const int* __restrict__ urev, const int* __restrict__ irev,
    const float* __restrict__ utab, const float* __restrict__ itab,
    float* __restrict__ sout)              // [2*B*L][64]
{
    int tid = threadIdx.x;
    int ln = tid & 63;
    int wv = tid >> 6;
    int gw = blockIdx.x * 4 + wv;          // [0, 2*B*L)
    int side = (gw >= Bn*Ln);
    int r = gw - (side ? Bn*Ln : 0);
    const int* rev = side ? irev : urev;
    const float* tab = side ? itab : utab;
    int i0 = rev[r*Nn + ln];
    int i1 = (ln < Nn - 64) ? rev[r*Nn + 64 + ln] : 0;
    int r0 = ln >> 4;                      // word-group 0..3
    int q4 = (ln & 15) << 2;               // dim quad 0,4,..,60
    float4 buf[25];
    #pragma unroll
    for (int j = 0; j < 25; ++j) {
        int n = r0 + 4*j;                  // lane group r0 covers n ≡ r0 (mod 4)
        int idx = (n < 64) ? __shfl(i0, n) : __shfl(i1, n - 64);
        buf[j] = *(const float4*)(tab + idx*Dn + q4);
    }
    float4 a = buf[0];
    #pragma unroll
    for (int j = 1; j < 25; ++j) { a.x += buf[j].x; a.y += buf[j].y; a.z += buf[j].z; a.w += buf[j].w; }
    // combine the 4 word-groups holding the same quad (lanes l, l^16, l^32, l^48)
    a.x += __shfl_xor(a.x, 16); a.y += __shfl_xor(a.y, 16); a.z += __shfl_xor(a.z, 16); a.w += __shfl_xor(a.w, 16);
    a.x += __shfl_xor(a.x, 32); a.y += __shfl_xor(a.y, 32); a.z += __shfl_xor(a.z, 32); a.w += __shfl_xor(a.w, 32);
    if (ln < 16) *(float4*)(sout + gw*Dn + q4) = a;
}

// ---------------- K1b: gate MLP on dense gather-sums ----------------
__global__ __launch_bounds__(256) void k1b_gate(
    const float* __restrict__ sin,
    const float* __restrict__ W1, const float* __restrict__ b1v,
    const float* __restrict__ W2, const float* __restrict__ b2v,
    float* __restrict__ ugo, float* __restrict__ igo)
{
    __shared__ float w1s[Dn][Dn+1];
    __shared__ float w2s[Dn][Dn+1];
    int tid = threadIdx.x;
    for (int k = tid; k < Dn*Dn; k += 256) {
        int r = k >> 6, c = k & 63;
        w1s[r][c] = W1[k]; w2s[r][c] = W2[k];
    }
    __syncthreads();
    int ln = tid & 63;
    int wv = tid >> 6;
    float b1 = b1v[ln], b2 = b2v[ln];
    int nW = gridDim.x * 4;
    for (int gw = blockIdx.x * 4 + wv; gw < 2*Bn*Ln; gw += nW) {
        float sv = sin[gw*Dn + ln];
        float t1 = b1, t2 = b2;
        #pragma unroll 8
        for (int d = 0; d < Dn; ++d) {
            float sd = __shfl(sv, d);
            t1 += sd * w1s[ln][d];
            t2 += sd * w2s[ln][d];
        }
        float g = (1.f / (1.f + expf(-t1))) * tanhf(t2);
        int side = (gw >= Bn*Ln);
        int r = gw - (side ? Bn*Ln : 0);
        (side ? igo : ugo)[r*Dn + ln] = g;
    }
}

// ---------------- K2: per-(b,h) pipeline, folded ----------------
__global__ __launch_bounds__(256) void k2_coatt(
    const int* __restrict__ urev, const int* __restrict__ irev,
    const int* __restrict__ uids, const int* __restrict__ iids,
    const int* __restrict__ ttype, const int* __restrict__ tmonth,
    const float* __restrict__ gu_all, const float* __restrict__ gi_all,
    const float* __restrict__ utab, const float* __restrict__ itab,
    const float* __restrict__ uid_tab, const float* __restrict__ iid_tab,
    const float* __restrict__ type_tab, const float* __restrict__ month_tab,
    const float* __restrict__ ug_in, const float* __restrict__ ig_in,
    const float* __restrict__ WMr, const float* __restrict__ bMr,
    const float* __restrict__ WiT_r, const float* __restrict__ bi_r,
    const float* __restrict__ GuT, const float* __restrict__ GiT,
    const float* __restrict__ gu_v, const float* __restrict__ gi_v,
    const float* __restrict__ M_f, const float* __restrict__ bu_f, const float* __restrict__ bi_f,
    const float* __restrict__ WuT_f, const float* __restrict__ WiT_f,
    const float* __restrict__ ufcT, const float* __restrict__ ufc_bv,
    const float* __restrict__ ifcT, const float* __restrict__ ifc_bv,
    float* __restrict__ feas, float* __restrict__ outp)
{
    __shared__ __align__(16) float big[13000];
    __shared__ float S[Ln][Ln];
    __shared__ int   lstar[2];
    __shared__ float vecs[4][Dn];     // uwbar, iwbar, wu, wi
    __shared__ float sc[2][Nn];
    __shared__ float uif[2][Dn];
    __shared__ float re[2][En], fe[4][En];
    __shared__ float u3[2][En], i3[4][En], A3[2][En];
    __shared__ float att[6];

    float* ug_sp = big;               // 1280
    float* ig_sp = big + 1280;        // 1280
    float* pu_sp = big + 2560;        // 2x20x64 = 2560
    float* pi_sp = big + 5120;        // 2560
    float* Ab_sp = big + 7680;        // 20x65 = 1300
    float* iv_sp = big + 8980;        // 1300
    float* uw    = big;               // 100x65 = 6500 (phase 2 overlay)
    float* iw    = big + 6500;        // 6500

    int tid = threadIdx.x;
    int bh = blockIdx.x;
    int b = bh / Hn;
    int h = bh - b*Hn;
    int ln = tid & 63;
    int wv = tid >> 6;

    if (tid < 4*En) {
        int rrow = tid >> 5, e = tid & 31;
        float v;
        if (rrow == 0) v = uid_tab[uids[b]*En + e];
        else if (rrow == 1) v = iid_tab[iids[b]*En + e];
        else if (rrow == 2) v = type_tab[ttype[b]*En + e];
        else v = month_tab[tmonth[b]*En + e];
        fe[rrow][e] = v;
    }
    {   // load gates (contiguous) as float4
        const float4* su = (const float4*)(ug_in + b*Ln*Dn);
        const float4* si = (const float4*)(ig_in + b*Ln*Dn);
        float4* du = (float4*)ug_sp;
        float4* di = (float4*)ig_sp;
        for (int k = tid; k < (Ln*Dn)/4; k += 256) { du[k] = su[k]; di[k] = si[k]; }
    }
    __syncthreads();

    // ---- phase 1: Ab = ug@WMr + bMr ; iv = ig@WiT + bi  (register-tiled over l) ----
    {
        int mat = wv & 1;               // 0: u->Ab via WMr, 1: i->iv via WiT
        int dh  = wv >> 1;              // d half
        const float* W = (mat ? (WiT_r + h*4096) : (WMr + h*4096)) + dh*32*Dn + ln;
        const float* X = (mat ? ig_sp : ug_sp) + dh*32;
        float acc[Ln];
        #pragma unroll
        for (int l = 0; l < Ln; ++l) acc[l] = 0.f;
        for (int dd = 0; dd < 32; dd += 4) {
            float w0 = W[(dd+0)*Dn];
            float w1 = W[(dd+1)*Dn];
            float w2 = W[(dd+2)*Dn];
            float w3 = W[(dd+3)*Dn];
            #pragma unroll
            for (int l = 0; l < Ln; ++l) {
                float4 x = *(const float4*)(X + l*Dn + dd);
                acc[l] += x.x*w0 + x.y*w1 + x.z*w2 + x.w*w3;
            }
        }
        float* po = (mat ? pi_sp : pu_sp) + dh*(Ln*Dn) + ln;
        #pragma unroll
        for (int l = 0; l < Ln; ++l) po[l*Dn] = acc[l];
    }
    __syncthreads();
    for (int k = tid; k < 2*Ln*Dn; k += 256) {
        int mm = (k >= Ln*Dn);
        int r = k - (mm ? Ln*Dn : 0);
        int l = r >> 6, ee = r & 63;
        if (!mm) Ab_sp[l*65 + ee] = pu_sp[l*Dn + ee] + pu_sp[Ln*Dn + l*Dn + ee] + bMr[h*Dn + ee];
        else     iv_sp[l*65 + ee] = pi_sp[l*Dn + ee] + pi_sp[Ln*Dn + l*Dn + ee] + bi_r[h*Dn + ee];
    }
    __syncthreads();
    for (int k = tid; k < Ln*Ln; k += 256) {
        int l = k / Ln, m = k - l*Ln;
        float a = 0.f;
        for (int e = 0; e < Dn; ++e) a += Ab_sp[l*65 + e] * iv_sp[m*65 + e];
        S[l][m] = a;
    }
    __syncthreads();
    // ---- argmax(rowmax + gumbel) via wave reduce ----
    if (wv == 0) {
        float v = -3.4e38f;
        if (ln < Ln) {
            float mx = S[ln][0];
            #pragma unroll
            for (int m = 1; m < Ln; ++m) mx = fmaxf(mx, S[ln][m]);
            v = mx + gu_all[(h*Bn + b)*Ln + ln];
        }
        int idx = ln;
        #pragma unroll
        for (int off = 32; off > 0; off >>= 1) {
            float ov = __shfl_down(v, off);
            int oi = __shfl_down(idx, off);
            if (ov > v || (ov == v && oi < idx)) { v = ov; idx = oi; }
        }
        if (ln == 0) lstar[0] = idx;
    } else if (wv == 1) {
        float v = -3.4e38f;
        if (ln < Ln) {
            float mx = S[0][ln];
            #pragma unroll
            for (int l = 1; l < Ln; ++l) mx = fmaxf(mx, S[l][ln]);
            v = mx + gi_all[(h*Bn + b)*Ln + ln];
        }
        int idx = ln;
        #pragma unroll
        for (int off = 32; off > 0; off >>= 1) {
            float ov = __shfl_down(v, off);
            int oi = __shfl_down(idx, off);
            if (ov > v || (ov == v && oi < idx)) { v = ov; idx = oi; }
        }
        if (ln == 0) lstar[1] = idx;
    }
    __syncthreads();
    // ---- phase 2: gather selected reviews' words (float4 reg-staged) ----
    {
        const int* up = urev + (b*Ln + lstar[0])*Nn;
        const int* ip = irev + (b*Ln + lstar[1])*Nn;
        for (int k = tid; k < (Nn*Dn)/4; k += 256) {
            int n = k >> 4, q = (k & 15) << 2;
            float4 vu = *(const float4*)(utab + up[n]*Dn + q);
            float4 vi = *(const float4*)(itab + ip[n]*Dn + q);
            float* du = uw + n*65 + q;
            du[0] = vu.x; du[1] = vu.y; du[2] = vu.z; du[3] = vu.w;
            float* di = iw + n*65 + q;
            di[0] = vi.x; di[1] = vi.y; di[2] = vi.z; di[3] = vi.w;
        }
    }
    __syncthreads();
    if (tid < Dn) {
        float a = 0.f;
        for (int n = 0; n < Nn; ++n) a += uw[n*65 + tid];
        vecs[0][tid] = a * (1.f/Nn);
    } else if (tid < 2*Dn) {
        int d = tid - Dn;
        float a = 0.f;
        for (int n = 0; n < Nn; ++n) a += iw[n*65 + d];
        vecs[1][d] = a * (1.f/Nn);
    }
    __syncthreads();
    // wu = GuT^T@iwbar + gu ; wi = GiT^T@uwbar + gi   (folded full chain)
    if (tid < Dn) {
        float a = gu_v[h*Dn + tid];
        for (int bb = 0; bb < Dn; ++bb) a += GuT[h*4096 + bb*Dn + tid] * vecs[1][bb];
        vecs[2][tid] = a;
    } else if (tid < 2*Dn) {
        int aa = tid - Dn;
        float a = gi_v[h*Dn + aa];
        for (int bb = 0; bb < Dn; ++bb) a += GiT[h*4096 + bb*Dn + aa] * vecs[0][bb];
        vecs[3][aa] = a;
    }
    __syncthreads();
    if (tid < Nn) {                        // u_score2[n] = uw[n]·wu (+const dropped)
        float a = 0.f;
        for (int d = 0; d < Dn; ++d) a += uw[tid*65 + d] * vecs[2][d];
        sc[0][tid] = a;
    } else if (tid >= 128 && tid < 128 + Nn) {
        int n = tid - 128;
        float a = 0.f;
        for (int d = 0; d < Dn; ++d) a += iw[n*65 + d] * vecs[3][d];
        sc[1][n] = a;
    }
    __syncthreads();
    // wave-parallel softmax over N=100 (waves 0 and 2)
    if (wv == 0 || wv == 2) {
        float* s = sc[wv >> 1];
        float x0 = s[ln];
        float x1 = (ln < Nn - 64) ? s[64 + ln] : -3.4e38f;
        float mx = fmaxf(x0, x1);
        #pragma unroll
        for (int off = 32; off > 0; off >>= 1) mx = fmaxf(mx, __shfl_xor(mx, off));
        float e0 = expf(x0 - mx);
        float e1 = (ln < Nn - 64) ? expf(x1 - mx) : 0.f;
        float sum = e0 + e1;
        #pragma unroll
        for (int off = 32; off > 0; off >>= 1) sum += __shfl_xor(sum, off);
        float inv = 1.f / sum;
        s[ln] = e0 * inv;
        if (ln < Nn - 64) s[64 + ln] = e1 * inv;
    }
    __syncthreads();
    if (tid < Dn) {
        float a = 0.f;
        for (int n = 0; n < Nn; ++n) a += sc[0][n] * uw[n*65 + tid];
        uif[0][tid] = a;
    } else if (tid < 2*Dn) {
        int d = tid - Dn;
        float a = 0.f;
        for (int n = 0; n < Nn; ++n) a += sc[1][n] * uw[n*65 + d];   // reference quirk: uw both times
        uif[1][d] = a;
    }
    __syncthreads();
    if (tid < En) {
        float a = ufc_bv[tid];
        for (int d = 0; d < Dn; ++d) a += uif[0][d] * ufcT[d*En + tid];
        re[0][tid] = fmaxf(a, 0.f);
    } else if (tid < 2*En) {
        int e = tid - En;
        float a = ifc_bv[e];
        for (int d = 0; d < Dn; ++d) a += uif[1][d] * ifcT[d*En + e];
        re[1][e] = fmaxf(a, 0.f);
    }
    __syncthreads();
    // ---- phase 3: coatt_f (2x4, avg pooling) ----
    const float* WuTf = WuT_f + h*En*En;
    const float* WiTf = WiT_f + h*En*En;
    const float* Mf   = M_f  + h*En*En;
    const float* buf_ = bu_f + h*En;
    const float* bif_ = bi_f + h*En;
    if (tid < 2*En) {
        int l = tid >> 5, e = tid & 31;
        float a = buf_[e];
        for (int j = 0; j < En; ++j) a += re[l][j] * WuTf[j*En + e];
        u3[l][e] = a;
    } else if (tid < 6*En) {
        int t2 = tid - 2*En;
        int m = t2 >> 5, e = t2 & 31;
        float a = bif_[e];
        for (int j = 0; j < En; ++j) a += fe[m][j] * WiTf[j*En + e];
        i3[m][e] = a;
    }
    __syncthreads();
    if (tid < 2*En) {
        int l = tid >> 5, e = tid & 31;
        float a = 0.f;
        for (int d = 0; d < En; ++d) a += u3[l][d] * Mf[d*En + e];
        A3[l][e] = a;
    }
    __syncthreads();
    if (tid == 0) {
        float S3[2][4];
        for (int l = 0; l < 2; ++l)
            for (int m = 0; m < 4; ++m) {
                float a = 0.f;
                for (int e = 0; e < En; ++e) a += A3[l][e] * i3[m][e];
                S3[l][m] = a;
            }
        float us0 = (S3[0][0] + S3[0][1] + S3[0][2] + S3[0][3]) * 0.25f;
        float us1 = (S3[1][0] + S3[1][1] + S3[1][2] + S3[1][3]) * 0.25f;
        float mx = fmaxf(us0, us1);
        float e0 = expf(us0 - mx), e1 = expf(us1 - mx);
        float inv = 1.f / (e0 + e1);
        att[0] = e0 * inv; att[1] = e1 * inv;
        float is_[4]; float mxi = -3.4e38f;
        for (int m = 0; m < 4; ++m) { is_[m] = (S3[0][m] + S3[1][m]) * 0.5f; mxi = fmaxf(mxi, is_[m]); }
        float ssum = 0.f, ee[4];
        for (int m = 0; m < 4; ++m) { ee[m] = expf(is_[m] - mxi); ssum += ee[m]; }
        float invi = 1.f / ssum;
        for (int m = 0; m < 4; ++m) att[2 + m] = ee[m] * invi;
    }
    __syncthreads();
    if (tid < En) {
        feas[b*96 + h*En + tid] = re[0][tid] * att[0];
    }
    if (h == 2) {
        if (tid >= 32 && tid < 64)        { int e = tid - 32;  outp[b*96 + e]              = fe[0][e] * att[2]; }
        else if (tid >= 64 && tid < 96)   { int e = tid - 64;  outp[b*96 + 32 + e]         = fe[2][e] * att[4]; }
        else if (tid >= 96 && tid < 128)  { int e = tid - 96;  outp[Bn*96 + b*96 + e]      = fe[1][e] * att[3]; }
        else if (tid >= 128 && tid < 160) { int e = tid - 128; outp[Bn*96 + b*96 + 32 + e] = fe[3][e] * att[5]; }
    }
}

// ---------------- K3: final linears ----------------
__global__ __launch_bounds__(64) void k3_final(
    const float* __restrict__ feas,
    const float* __restrict__ u_fcT, const float* __restrict__ u_fc_bv,
    const float* __restrict__ i_fcT, const float* __restrict__ i_fc_bv,
    float* __restrict__ outp)
{
    __shared__ float f[96];
    int b = blockIdx.x, tid = threadIdx.x;
    for (int k = tid; k < 96; k += 64) f[k] = feas[b*96 + k];
    __syncthreads();
    if (tid < 32) {
        float a = u_fc_bv[tid];
        for (int k = 0; k < 96; ++k) a += f[k] * u_fcT[k*32 + tid];
        outp[b*96 + 64 + tid] = a;
    } else {
        int e = tid - 32;
        float a = i_fc_bv[e];
        for (int k = 0; k < 96; ++k) a += f[k] * i_fcT[k*32 + e];
        outp[Bn*96 + b*96 + 64 + e] = a;
    }
}

extern "C" void kernel_launch(void* const* d_in, const int* in_sizes, int n_in,
                              void* d_out, int out_size, void* d_ws, size_t ws_size,
                              hipStream_t stream)
{
    const int* urev = (const int*)d_in[0];
    const int* irev = (const int*)d_in[1];
    const int* uids = (const int*)d_in[2];
    const int* iids = (const int*)d_in[3];
    const int* ttype = (const int*)d_in[4];
    const int* tmonth = (const int*)d_in[5];
    const float* gu = (const float*)d_in[6];
    const float* gi = (const float*)d_in[7];
    const float* utab = (const float*)d_in[8];
    const float* itab = (const float*)d_in[9];
    const float* uid_tab = (const float*)d_in[10];
    const float* iid_tab = (const float*)d_in[11];
    const float* type_tab = (const float*)d_in[12];
    const float* month_tab = (const float*)d_in[13];
    const float* fc_g1_w = (const float*)d_in[14];
    const float* fc_g1_b = (const float*)d_in[15];
    const float* fc_g2_w = (const float*)d_in[16];
    const float* fc_g2_b = (const float*)d_in[17];
    const float* M_r = (const float*)d_in[18];
    const float* Wu_r = (const float*)d_in[19];
    const float* bu_r = (const float*)d_in[20];
    const float* Wi_r = (const float*)d_in[21];
    const float* bi_r = (const float*)d_in[22];
    const float* M_w = (const float*)d_in[23];
    const float* Wu_w = (const float*)d_in[24];
    const float* bu_w = (const float*)d_in[25];
    const float* Wi_w = (const float*)d_in[26];
    const float* bi_w = (const float*)d_in[27];
    const float* M_f = (const float*)d_in[28];
    const float* Wu_f = (const float*)d_in[29];
    const float* bu_f = (const float*)d_in[30];
    const float* Wi_f = (const float*)d_in[31];
    const float* bi_f = (const float*)d_in[32];
    const float* ufc_w = (const float*)d_in[33];
    const float* ufc_b = (const float*)d_in[34];
    const float* ifc_w = (const float*)d_in[35];
    const float* ifc_b = (const float*)d_in[36];
    const float* u_fc_w = (const float*)d_in[37];
    const float* u_fc_b = (const float*)d_in[38];
    const float* i_fc_w = (const float*)d_in[39];
    const float* i_fc_b = (const float*)d_in[40];
    (void)in_sizes; (void)n_in; (void)out_size; (void)ws_size;

    float* ws = (float*)d_ws;
    float* ugo   = ws;                         // B*L*D
    float* igo   = ugo + Bn*Ln*Dn;
    float* sgat  = igo + Bn*Ln*Dn;             // 2*B*L*D gather sums
    float* feas  = sgat + 2*Bn*Ln*Dn;          // B*96
    float* WiT_r = feas + Bn*96;
    float* WMr   = WiT_r + Hn*Dn*Dn;
    float* bMr   = WMr + Hn*Dn*Dn;
    float* P     = bMr + Hn*Dn;
    float* Q     = P + Hn*Dn*Dn;
    float* MB    = Q + Hn*Dn*Dn;
    float* MTB   = MB + Hn*Dn;
    float* GuT   = MTB + Hn*Dn;
    float* GiT   = GuT + Hn*Dn*Dn;
    float* gu_v  = GiT + Hn*Dn*Dn;
    float* gi_v  = gu_v + Hn*Dn;
    float* WuT_f = gi_v + Hn*Dn;
    float* WiT_f = WuT_f + Hn*En*En;
    float* ufcT  = WiT_f + Hn*En*En;
    float* ifcT  = ufcT + Dn*En;
    float* u_fcT = ifcT + Dn*En;
    float* i_fcT = u_fcT + 96*En;

    hipLaunchKernelGGL(k0a_prep, dim3(48), dim3(256), 0, stream,
        M_r, Wu_r, bu_r, Wi_r, M_w, Wu_w, bu_w, Wi_w, bi_w,
        Wu_f, Wi_f, ufc_w, ifc_w, u_fc_w, i_fc_w,
        WiT_r, WMr, bMr, P, Q, MB, MTB, WuT_f, WiT_f, ufcT, ifcT, u_fcT, i_fcT);

    hipLaunchKernelGGL(k0b_prep, dim3(48), dim3(256), 0, stream,
        Wu_w, Wi_w, P, Q, MB, MTB, GuT, GiT, gu_v, gi_v);

    hipLaunchKernelGGL(k1a_gsum, dim3(2*Bn*Ln/4), dim3(256), 0, stream,
        urev, irev, utab, itab, sgat);

    hipLaunchKernelGGL(k1b_gate, dim3(512), dim3(256), 0, stream,
        sgat, fc_g1_w, fc_g1_b, fc_g2_w, fc_g2_b, ugo, igo);

    hipLaunchKernelGGL(k2_coatt, dim3(Bn*Hn), dim3(256), 0, stream,
        urev, irev, uids, iids, ttype, tmonth, gu, gi, utab, itab,
        uid_tab, iid_tab, type_tab, month_tab, ugo, igo,
        WMr, bMr, WiT_r, bi_r, GuT, GiT, gu_v, gi_v,
        M_f, bu_f, bi_f, WuT_f, WiT_f,
        ufcT, ufc_b, ifcT, ifc_b, feas, (float*)d_out);

    hipLaunchKernelGGL(k3_final, dim3(Bn), dim3(64), 0, stream,
        feas, u_fcT, u_fc_b, i_fcT, i_fc_b, (float*)d_out);
}